// Round 3
// baseline (212.491 us; speedup 1.0000x reference)
//
#include <hip/hip_runtime.h>

__device__ __forceinline__ float2 cadd(float2 a, float2 b) { return make_float2(a.x + b.x, a.y + b.y); }
__device__ __forceinline__ float2 csub(float2 a, float2 b) { return make_float2(a.x - b.x, a.y - b.y); }
__device__ __forceinline__ float2 cmul(float2 w, float2 z) {
    return make_float2(w.x * z.x - w.y * z.y, w.x * z.y + w.y * z.x);
}

// In-place butterfly network equivalent of the reference:
//   stage t (0..22): pairs (i, i + 2^(22-t)); z'[i] = z[i] + w*z[i+D]; z'[i+D] = z[i] - w*z[i+D]
//   w = weight[ bitrev_t(i >> (23-t)) * 2^(22-t) ];  final: out[o] = z[bitrev23(o)]
// Pass A: t=0..7 (bits 22..15) | Pass B: t=8..15 (bits 14..7) | Pass C: t=16..22 (bits 6..0) + bitrev store.
// R2: LDS halved in B (8 l-cols) and C (16 chunks) -> 8 blocks/CU for latency hiding.

__global__ __launch_bounds__(256) void fft_pass_a(const float* __restrict__ in,
                                                  const float2* __restrict__ wt,
                                                  float2* __restrict__ out)
{
    __shared__ float2 L[4096];   // [g*16 + c], 32 KB
    const int tid = threadIdx.x;
    const int l0  = blockIdx.x << 4;
    const int c   = tid & 15;
    const int qb  = tid >> 4;

    float2 pw1[4], pw2a[4], pw2b[4];
#pragma unroll
    for (int k = 0; k < 4; ++k) { pw1[k] = wt[0]; pw2a[k] = wt[0]; pw2b[k] = wt[1 << 21]; }

    {
        const int c4 = tid & 3, gg = tid >> 2;
#pragma unroll
        for (int k = 0; k < 4; ++k) {
            const int g = gg + (k << 6);
            const float4 v = *reinterpret_cast<const float4*>(in + ((size_t)g << 15) + l0 + (c4 << 2));
            const int base = (g << 4) + (c4 << 2);
            L[base + 0] = make_float2(v.x, 0.f);
            L[base + 1] = make_float2(v.y, 0.f);
            L[base + 2] = make_float2(v.z, 0.f);
            L[base + 3] = make_float2(v.w, 0.f);
        }
    }
    __syncthreads();

#pragma unroll
    for (int rho = 0; rho < 4; ++rho) {
        const int s = rho << 1, H = 128 >> s, Q = H >> 1, lo = 6 - s;
        float2 nw1[4], nw2a[4], nw2b[4];
        if (rho < 3) {
            const int s2 = s + 2, lo2 = 6 - s2;
#pragma unroll
            for (int k = 0; k < 4; ++k) {
                const int qi = (qb << 2) + k;
                const int b  = ((qi >> lo2) << (lo2 + 2)) | (qi & ((1 << lo2) - 1));
                const int jl = (int)(__brev((unsigned)(b >> (8 - s2))) >> (32 - s2));
                const int e  = jl << (21 - s2);
                nw1[k] = wt[e << 1]; nw2a[k] = wt[e]; nw2b[k] = wt[e + (1 << 21)];
            }
        }
#pragma unroll
        for (int k = 0; k < 4; ++k) {
            const int qi = (qb << 2) + k;
            const int b  = ((qi >> lo) << (lo + 2)) | (qi & ((1 << lo) - 1));
            const int iA = (b << 4) + c;
            const float2 A  = L[iA];
            const float2 Bv = L[iA + (Q << 4)];
            const float2 Cv = L[iA + (H << 4)];
            const float2 Dv = L[iA + ((H + Q) << 4)];
            const float2 pC = cmul(pw1[k], Cv), pD = cmul(pw1[k], Dv);
            const float2 tA = cadd(A, pC),  tC = csub(A, pC);
            const float2 tB = cadd(Bv, pD), tD = csub(Bv, pD);
            const float2 p2 = cmul(pw2a[k], tB);
            const float2 p3 = cmul(pw2b[k], tD);
            L[iA]                  = cadd(tA, p2);
            L[iA + (Q << 4)]       = csub(tA, p2);
            L[iA + (H << 4)]       = cadd(tC, p3);
            L[iA + ((H + Q) << 4)] = csub(tC, p3);
        }
        __syncthreads();
        if (rho < 3) {
#pragma unroll
            for (int k = 0; k < 4; ++k) { pw1[k] = nw1[k]; pw2a[k] = nw2a[k]; pw2b[k] = nw2b[k]; }
        }
    }

    {
        const int c2 = tid & 7, gg = tid >> 3;
#pragma unroll
        for (int k = 0; k < 8; ++k) {
            const int g  = gg + (k << 5);
            const int li = (g << 4) + (c2 << 1);
            const float2 a0 = L[li], a1 = L[li + 1];
            *reinterpret_cast<float4*>(out + ((size_t)g << 15) + l0 + (c2 << 1)) =
                make_float4(a0.x, a0.y, a1.x, a1.y);
        }
    }
}

__global__ __launch_bounds__(256, 8) void fft_pass_b(const float2* __restrict__ in,
                                                     const float2* __restrict__ wt,
                                                     float2* __restrict__ out)
{
    __shared__ float2 L[2048];   // [g*8 + c], 16 KB -> 8 blocks/CU
    const int tid  = threadIdx.x;
    const int h    = blockIdx.x >> 4;           // 0..255, bits 22..15
    const int l0   = (blockIdx.x & 15) << 3;    // bits 6..0 base, 8 per WG
    const size_t base = ((size_t)h << 15) + l0;
    const int hrev = (int)(__brev((unsigned)h) >> 24);
    const int c  = tid & 7;
    const int qb = tid >> 3;                    // 0..31

    float2 pw1[2], pw2a[2], pw2b[2];
    {
        const int e0 = hrev << 13;
#pragma unroll
        for (int k = 0; k < 2; ++k) { pw1[k] = wt[e0 << 1]; pw2a[k] = wt[e0]; pw2b[k] = wt[e0 + (1 << 21)]; }
    }

    // ---- load: 256 g-rows x 8 complex (64 B/row) ----
    {
        const int c4 = tid & 3, gg = tid >> 2;  // 4 float4 slots per row
#pragma unroll
        for (int k = 0; k < 4; ++k) {
            const int g = gg + (k << 6);
            const float4 v = *reinterpret_cast<const float4*>(in + base + (g << 7) + (c4 << 1));
            const int li = (g << 3) + (c4 << 1);
            L[li]     = make_float2(v.x, v.y);
            L[li + 1] = make_float2(v.z, v.w);
        }
    }
    __syncthreads();

#pragma unroll
    for (int rho = 0; rho < 4; ++rho) {
        const int s = rho << 1, H = 128 >> s, Q = H >> 1, lo = 6 - s;
        float2 nw1[2], nw2a[2], nw2b[2];
        if (rho < 3) {
            const int s2 = s + 2, lo2 = 6 - s2;
#pragma unroll
            for (int k = 0; k < 2; ++k) {
                const int qi = (qb << 1) + k;
                const int b  = ((qi >> lo2) << (lo2 + 2)) | (qi & ((1 << lo2) - 1));
                const int jl = (int)(__brev((unsigned)(b >> (8 - s2))) >> (32 - s2));
                const int e  = (hrev << (13 - s2)) + (jl << (21 - s2));
                nw1[k] = wt[e << 1]; nw2a[k] = wt[e]; nw2b[k] = wt[e + (1 << 21)];
            }
        }
#pragma unroll
        for (int k = 0; k < 2; ++k) {
            const int qi = (qb << 1) + k;       // 0..63
            const int b  = ((qi >> lo) << (lo + 2)) | (qi & ((1 << lo) - 1));
            const int iA = (b << 3) + c;
            const float2 A  = L[iA];
            const float2 Bv = L[iA + (Q << 3)];
            const float2 Cv = L[iA + (H << 3)];
            const float2 Dv = L[iA + ((H + Q) << 3)];
            const float2 pC = cmul(pw1[k], Cv), pD = cmul(pw1[k], Dv);
            const float2 tA = cadd(A, pC),  tC = csub(A, pC);
            const float2 tB = cadd(Bv, pD), tD = csub(Bv, pD);
            const float2 p2 = cmul(pw2a[k], tB);
            const float2 p3 = cmul(pw2b[k], tD);
            L[iA]                  = cadd(tA, p2);
            L[iA + (Q << 3)]       = csub(tA, p2);
            L[iA + (H << 3)]       = cadd(tC, p3);
            L[iA + ((H + Q) << 3)] = csub(tC, p3);
        }
        __syncthreads();
        if (rho < 3) {
#pragma unroll
            for (int k = 0; k < 2; ++k) { pw1[k] = nw1[k]; pw2a[k] = nw2a[k]; pw2b[k] = nw2b[k]; }
        }
    }

    {
        const int c4 = tid & 3, gg = tid >> 2;
#pragma unroll
        for (int k = 0; k < 4; ++k) {
            const int g  = gg + (k << 6);
            const int li = (g << 3) + (c4 << 1);
            const float2 a0 = L[li], a1 = L[li + 1];
            *reinterpret_cast<float4*>(out + base + (g << 7) + (c4 << 1)) =
                make_float4(a0.x, a0.y, a1.x, a1.y);
        }
    }
}

__global__ __launch_bounds__(256, 8) void fft_pass_c(const float2* __restrict__ in,
                                                     const float2* __restrict__ wt,
                                                     float2* __restrict__ out)
{
    __shared__ float2 L[16 * 129];    // 16 chunks, pitch 129 -> ~16.1 KB, 8 blocks/CU
    const int tid = threadIdx.x;
    const int h0  = blockIdx.x;       // 0..4095

    const int lam = tid & 15;
    const int bq  = tid >> 4;         // 0..15
    const int rH  = (h0 << 4) + lam;  // rev16(H) for this lane's chunk

    float2 pw1[2], pw2a[2], pw2b[2];
#pragma unroll
    for (int k = 0; k < 2; ++k) {
        pw1[k]  = wt[rH << 6];
        pw2a[k] = wt[rH << 5];
        pw2b[k] = wt[(rH << 5) + (1 << 21)];
    }

    // ---- load: 16 chunks of 128 contiguous complex; chunk id H = rev16(h0*16+lm) ----
    {
        const int f  = tid & 63;      // float4 slot within chunk (wave = 1 KB contiguous)
        const int ll = tid >> 6;      // 0..3
#pragma unroll
        for (int k = 0; k < 4; ++k) {
            const int lm = ll + (k << 2);
            const int H  = (int)(__brev((unsigned)((h0 << 4) + lm)) >> 16);
            const float4 v = *reinterpret_cast<const float4*>(in + ((size_t)H << 7) + (f << 1));
            const int li = lm * 129 + (f << 1);
            L[li]     = make_float2(v.x, v.y);
            L[li + 1] = make_float2(v.z, v.w);
        }
    }
    __syncthreads();

    // ---- stages 16..21 as 3 radix-4 rounds ----
    float2 pr2[4];
#pragma unroll
    for (int rho = 0; rho < 3; ++rho) {
        const int s = rho << 1, H = 64 >> s, Q = H >> 1, lo = 5 - s;
        float2 nw1[2], nw2a[2], nw2b[2];
        if (rho < 2) {
            const int s2 = s + 2, lo2 = 5 - s2;
#pragma unroll
            for (int k = 0; k < 2; ++k) {
                const int qi = (bq << 1) + k;
                const int b  = ((qi >> lo2) << (lo2 + 2)) | (qi & ((1 << lo2) - 1));
                const int jl = (int)(__brev((unsigned)(b >> (7 - s2))) >> (32 - s2));
                const int e  = (rH << (5 - s2)) + (jl << (21 - s2));
                nw1[k] = wt[e << 1]; nw2a[k] = wt[e]; nw2b[k] = wt[e + (1 << 21)];
            }
        } else {
#pragma unroll
            for (int k = 0; k < 4; ++k) {
                const int pb = (bq << 2) + k;
                const int jl = (int)(__brev((unsigned)pb) >> 26);
                pr2[k] = wt[rH + (jl << 16)];
            }
        }
#pragma unroll
        for (int k = 0; k < 2; ++k) {
            const int qi = (bq << 1) + k;     // 0..31
            const int b  = ((qi >> lo) << (lo + 2)) | (qi & ((1 << lo) - 1));
            const int iA = lam * 129 + b;
            const float2 A  = L[iA];
            const float2 Bv = L[iA + Q];
            const float2 Cv = L[iA + H];
            const float2 Dv = L[iA + H + Q];
            const float2 pC = cmul(pw1[k], Cv), pD = cmul(pw1[k], Dv);
            const float2 tA = cadd(A, pC),  tC = csub(A, pC);
            const float2 tB = cadd(Bv, pD), tD = csub(Bv, pD);
            const float2 p2 = cmul(pw2a[k], tB);
            const float2 p3 = cmul(pw2b[k], tD);
            L[iA]         = cadd(tA, p2);
            L[iA + Q]     = csub(tA, p2);
            L[iA + H]     = cadd(tC, p3);
            L[iA + H + Q] = csub(tC, p3);
        }
        __syncthreads();
        if (rho < 2) {
#pragma unroll
            for (int k = 0; k < 2; ++k) { pw1[k] = nw1[k]; pw2a[k] = nw2a[k]; pw2b[k] = nw2b[k]; }
        }
    }

    // ---- final radix-2 stage (t=22, stride 1) ----
    {
#pragma unroll
        for (int k = 0; k < 4; ++k) {
            const int pb = (bq << 2) + k;     // 0..63
            const int b  = pb << 1;
            const int iA = lam * 129 + b;
            const float2 A  = L[iA];
            const float2 Bv = L[iA + 1];
            const float2 p  = cmul(pr2[k], Bv);
            L[iA]     = cadd(A, p);
            L[iA + 1] = csub(A, p);
        }
    }
    __syncthreads();

    // ---- store with bit-reversal: out[rev7(g)*2^16 + h0*16 + lam] = L[lam][g] ----
    {
        const int l2 = (tid & 7) << 1;        // even lam (0..14)
        const int gb = tid >> 3;              // 0..31
#pragma unroll
        for (int k = 0; k < 4; ++k) {
            const int g    = gb + (k << 5);   // 0..127
            const int grev = (int)(__brev((unsigned)g) >> 25);   // rev7(g)
            const float2 a0 = L[l2 * 129 + g];
            const float2 a1 = L[(l2 + 1) * 129 + g];
            const size_t o = ((size_t)grev << 16) + (h0 << 4) + l2;
            *reinterpret_cast<float4*>(out + o) = make_float4(a0.x, a0.y, a1.x, a1.y);
        }
    }
}

extern "C" void kernel_launch(void* const* d_in, const int* in_sizes, int n_in,
                              void* d_out, int out_size, void* d_ws, size_t ws_size,
                              hipStream_t stream)
{
    (void)in_sizes; (void)n_in; (void)out_size; (void)ws_size;
    const float*  in = (const float*)d_in[0];
    const float2* wt = (const float2*)d_in[1];
    float2* outc = (float2*)d_out;
    float2* wsc  = (float2*)d_ws;

    fft_pass_a<<<2048, 256, 0, stream>>>(in, wt, outc);   // stages 0..7  : in  -> out
    fft_pass_b<<<4096, 256, 0, stream>>>(outc, wt, wsc);  // stages 8..15 : out -> ws
    fft_pass_c<<<4096, 256, 0, stream>>>(wsc, wt, outc);  // stages 16..22: ws  -> out (+bitrev)
}

// Round 4
// 180.617 us; speedup vs baseline: 1.1765x; 1.1765x over previous
//
#include <hip/hip_runtime.h>
#include <hip/hip_fp16.h>

__device__ __forceinline__ float2 cadd(float2 a, float2 b) { return make_float2(a.x + b.x, a.y + b.y); }
__device__ __forceinline__ float2 csub(float2 a, float2 b) { return make_float2(a.x - b.x, a.y - b.y); }
__device__ __forceinline__ float2 cmul(float2 w, float2 z) {
    return make_float2(w.x * z.x - w.y * z.y, w.x * z.y + w.y * z.x);
}
__device__ __forceinline__ unsigned pk(float2 z) {
    __half2 h = __floats2half2_rn(z.x, z.y);
    return *reinterpret_cast<unsigned*>(&h);
}
__device__ __forceinline__ float2 upk(unsigned u) {
    __half2 h = *reinterpret_cast<__half2*>(&u);
    return __half22float2(h);
}

// In-place butterfly network equivalent of the reference:
//   stage t (0..22): pairs (i, i + 2^(22-t)); z'[i] = z[i] + w*z[i+D]; z'[i+D] = z[i] - w*z[i+D]
//   w = weight[ bitrev_t(i >> (23-t)) * 2^(22-t) ];  final: out[o] = z[bitrev23(o)]
// Pass A: t=0..7 (bits 22..15) | Pass B: t=8..15 (bits 14..7) | Pass C: t=16..22 (bits 6..0) + bitrev store.
// R4: inter-pass arrays stored as packed fp16 complex (half2); compute + LDS stay fp32.
//     B reverted to 16-col tile (R3's 8-col was a regression).

__global__ __launch_bounds__(256) void fft_pass_a(const float* __restrict__ in,
                                                  const float2* __restrict__ wt,
                                                  uint4* __restrict__ outp)
{
    __shared__ float2 L[4096];   // [g*16 + c], 32 KB
    const int tid = threadIdx.x;
    const int l0  = blockIdx.x << 4;
    const int c   = tid & 15;
    const int qb  = tid >> 4;

    float2 pw1[4], pw2a[4], pw2b[4];
#pragma unroll
    for (int k = 0; k < 4; ++k) { pw1[k] = wt[0]; pw2a[k] = wt[0]; pw2b[k] = wt[1 << 21]; }

    // ---- load: real input, imag = 0 ----
    {
        const int c4 = tid & 3, gg = tid >> 2;
#pragma unroll
        for (int k = 0; k < 4; ++k) {
            const int g = gg + (k << 6);
            const float4 v = *reinterpret_cast<const float4*>(in + ((size_t)g << 15) + l0 + (c4 << 2));
            const int base = (g << 4) + (c4 << 2);
            L[base + 0] = make_float2(v.x, 0.f);
            L[base + 1] = make_float2(v.y, 0.f);
            L[base + 2] = make_float2(v.z, 0.f);
            L[base + 3] = make_float2(v.w, 0.f);
        }
    }
    __syncthreads();

#pragma unroll
    for (int rho = 0; rho < 4; ++rho) {
        const int s = rho << 1, H = 128 >> s, Q = H >> 1, lo = 6 - s;
        float2 nw1[4], nw2a[4], nw2b[4];
        if (rho < 3) {
            const int s2 = s + 2, lo2 = 6 - s2;
#pragma unroll
            for (int k = 0; k < 4; ++k) {
                const int qi = (qb << 2) + k;
                const int b  = ((qi >> lo2) << (lo2 + 2)) | (qi & ((1 << lo2) - 1));
                const int jl = (int)(__brev((unsigned)(b >> (8 - s2))) >> (32 - s2));
                const int e  = jl << (21 - s2);
                nw1[k] = wt[e << 1]; nw2a[k] = wt[e]; nw2b[k] = wt[e + (1 << 21)];
            }
        }
#pragma unroll
        for (int k = 0; k < 4; ++k) {
            const int qi = (qb << 2) + k;
            const int b  = ((qi >> lo) << (lo + 2)) | (qi & ((1 << lo) - 1));
            const int iA = (b << 4) + c;
            const float2 A  = L[iA];
            const float2 Bv = L[iA + (Q << 4)];
            const float2 Cv = L[iA + (H << 4)];
            const float2 Dv = L[iA + ((H + Q) << 4)];
            const float2 pC = cmul(pw1[k], Cv), pD = cmul(pw1[k], Dv);
            const float2 tA = cadd(A, pC),  tC = csub(A, pC);
            const float2 tB = cadd(Bv, pD), tD = csub(Bv, pD);
            const float2 p2 = cmul(pw2a[k], tB);
            const float2 p3 = cmul(pw2b[k], tD);
            L[iA]                  = cadd(tA, p2);
            L[iA + (Q << 4)]       = csub(tA, p2);
            L[iA + (H << 4)]       = cadd(tC, p3);
            L[iA + ((H + Q) << 4)] = csub(tC, p3);
        }
        __syncthreads();
        if (rho < 3) {
#pragma unroll
            for (int k = 0; k < 4; ++k) { pw1[k] = nw1[k]; pw2a[k] = nw2a[k]; pw2b[k] = nw2b[k]; }
        }
    }

    // ---- store packed fp16: 4 complex per uint4 ----
    {
        const int c4 = tid & 3, gg = tid >> 2;
#pragma unroll
        for (int k = 0; k < 4; ++k) {
            const int g  = gg + (k << 6);
            const int li = (g << 4) + (c4 << 2);
            uint4 v;
            v.x = pk(L[li]); v.y = pk(L[li + 1]); v.z = pk(L[li + 2]); v.w = pk(L[li + 3]);
            outp[((size_t)g << 13) + (l0 >> 2) + c4] = v;
        }
    }
}

__global__ __launch_bounds__(256) void fft_pass_b(const uint4* __restrict__ inp,
                                                  const float2* __restrict__ wt,
                                                  uint4* __restrict__ outp)
{
    __shared__ float2 L[4096];   // [g*16 + c], 32 KB
    const int tid  = threadIdx.x;
    const int h    = blockIdx.x >> 3;           // 0..255, bits 22..15
    const int l0   = (blockIdx.x & 7) << 4;     // bits 6..0 base, 16 per WG
    const int hrev = (int)(__brev((unsigned)h) >> 24);
    const int c  = tid & 15;
    const int qb = tid >> 4;
    const size_t pbase = ((size_t)h << 13) + (l0 >> 2);  // uint4 index base

    float2 pw1[4], pw2a[4], pw2b[4];
    {
        const int e0 = hrev << 13;
#pragma unroll
        for (int k = 0; k < 4; ++k) { pw1[k] = wt[e0 << 1]; pw2a[k] = wt[e0]; pw2b[k] = wt[e0 + (1 << 21)]; }
    }

    // ---- load packed fp16 ----
    {
        const int c4 = tid & 3, gg = tid >> 2;
#pragma unroll
        for (int k = 0; k < 4; ++k) {
            const int g = gg + (k << 6);
            const uint4 v = inp[pbase + (g << 5) + c4];
            const int li = (g << 4) + (c4 << 2);
            L[li]     = upk(v.x);
            L[li + 1] = upk(v.y);
            L[li + 2] = upk(v.z);
            L[li + 3] = upk(v.w);
        }
    }
    __syncthreads();

#pragma unroll
    for (int rho = 0; rho < 4; ++rho) {
        const int s = rho << 1, H = 128 >> s, Q = H >> 1, lo = 6 - s;
        float2 nw1[4], nw2a[4], nw2b[4];
        if (rho < 3) {
            const int s2 = s + 2, lo2 = 6 - s2;
#pragma unroll
            for (int k = 0; k < 4; ++k) {
                const int qi = (qb << 2) + k;
                const int b  = ((qi >> lo2) << (lo2 + 2)) | (qi & ((1 << lo2) - 1));
                const int jl = (int)(__brev((unsigned)(b >> (8 - s2))) >> (32 - s2));
                const int e  = (hrev << (13 - s2)) + (jl << (21 - s2));
                nw1[k] = wt[e << 1]; nw2a[k] = wt[e]; nw2b[k] = wt[e + (1 << 21)];
            }
        }
#pragma unroll
        for (int k = 0; k < 4; ++k) {
            const int qi = (qb << 2) + k;
            const int b  = ((qi >> lo) << (lo + 2)) | (qi & ((1 << lo) - 1));
            const int iA = (b << 4) + c;
            const float2 A  = L[iA];
            const float2 Bv = L[iA + (Q << 4)];
            const float2 Cv = L[iA + (H << 4)];
            const float2 Dv = L[iA + ((H + Q) << 4)];
            const float2 pC = cmul(pw1[k], Cv), pD = cmul(pw1[k], Dv);
            const float2 tA = cadd(A, pC),  tC = csub(A, pC);
            const float2 tB = cadd(Bv, pD), tD = csub(Bv, pD);
            const float2 p2 = cmul(pw2a[k], tB);
            const float2 p3 = cmul(pw2b[k], tD);
            L[iA]                  = cadd(tA, p2);
            L[iA + (Q << 4)]       = csub(tA, p2);
            L[iA + (H << 4)]       = cadd(tC, p3);
            L[iA + ((H + Q) << 4)] = csub(tC, p3);
        }
        __syncthreads();
        if (rho < 3) {
#pragma unroll
            for (int k = 0; k < 4; ++k) { pw1[k] = nw1[k]; pw2a[k] = nw2a[k]; pw2b[k] = nw2b[k]; }
        }
    }

    // ---- store packed fp16 ----
    {
        const int c4 = tid & 3, gg = tid >> 2;
#pragma unroll
        for (int k = 0; k < 4; ++k) {
            const int g  = gg + (k << 6);
            const int li = (g << 4) + (c4 << 2);
            uint4 v;
            v.x = pk(L[li]); v.y = pk(L[li + 1]); v.z = pk(L[li + 2]); v.w = pk(L[li + 3]);
            outp[pbase + (g << 5) + c4] = v;
        }
    }
}

__global__ __launch_bounds__(256, 8) void fft_pass_c(const uint4* __restrict__ inp,
                                                     const float2* __restrict__ wt,
                                                     float2* __restrict__ out)
{
    __shared__ float2 L[16 * 129];    // 16 chunks, pitch 129 -> ~16.1 KB, 8 blocks/CU
    const int tid = threadIdx.x;
    const int h0  = blockIdx.x;       // 0..4095

    const int lam = tid & 15;
    const int bq  = tid >> 4;         // 0..15
    const int rH  = (h0 << 4) + lam;  // rev16(H) for this lane's chunk

    float2 pw1[2], pw2a[2], pw2b[2];
#pragma unroll
    for (int k = 0; k < 2; ++k) {
        pw1[k]  = wt[rH << 6];
        pw2a[k] = wt[rH << 5];
        pw2b[k] = wt[(rH << 5) + (1 << 21)];
    }

    // ---- load packed fp16: 16 chunks of 128 complex (512 B granules) ----
    {
        const int f  = tid & 31;      // uint4 slot within chunk
        const int ll = tid >> 5;      // 0..7
#pragma unroll
        for (int k = 0; k < 2; ++k) {
            const int lm = ll + (k << 3);
            const int H  = (int)(__brev((unsigned)((h0 << 4) + lm)) >> 16);
            const uint4 v = inp[((size_t)H << 5) + f];
            const int li = lm * 129 + (f << 2);
            L[li]     = upk(v.x);
            L[li + 1] = upk(v.y);
            L[li + 2] = upk(v.z);
            L[li + 3] = upk(v.w);
        }
    }
    __syncthreads();

    // ---- stages 16..21 as 3 radix-4 rounds ----
    float2 pr2[4];
#pragma unroll
    for (int rho = 0; rho < 3; ++rho) {
        const int s = rho << 1, H = 64 >> s, Q = H >> 1, lo = 5 - s;
        float2 nw1[2], nw2a[2], nw2b[2];
        if (rho < 2) {
            const int s2 = s + 2, lo2 = 5 - s2;
#pragma unroll
            for (int k = 0; k < 2; ++k) {
                const int qi = (bq << 1) + k;
                const int b  = ((qi >> lo2) << (lo2 + 2)) | (qi & ((1 << lo2) - 1));
                const int jl = (int)(__brev((unsigned)(b >> (7 - s2))) >> (32 - s2));
                const int e  = (rH << (5 - s2)) + (jl << (21 - s2));
                nw1[k] = wt[e << 1]; nw2a[k] = wt[e]; nw2b[k] = wt[e + (1 << 21)];
            }
        } else {
#pragma unroll
            for (int k = 0; k < 4; ++k) {
                const int pb = (bq << 2) + k;
                const int jl = (int)(__brev((unsigned)pb) >> 26);
                pr2[k] = wt[rH + (jl << 16)];
            }
        }
#pragma unroll
        for (int k = 0; k < 2; ++k) {
            const int qi = (bq << 1) + k;     // 0..31
            const int b  = ((qi >> lo) << (lo + 2)) | (qi & ((1 << lo) - 1));
            const int iA = lam * 129 + b;
            const float2 A  = L[iA];
            const float2 Bv = L[iA + Q];
            const float2 Cv = L[iA + H];
            const float2 Dv = L[iA + H + Q];
            const float2 pC = cmul(pw1[k], Cv), pD = cmul(pw1[k], Dv);
            const float2 tA = cadd(A, pC),  tC = csub(A, pC);
            const float2 tB = cadd(Bv, pD), tD = csub(Bv, pD);
            const float2 p2 = cmul(pw2a[k], tB);
            const float2 p3 = cmul(pw2b[k], tD);
            L[iA]         = cadd(tA, p2);
            L[iA + Q]     = csub(tA, p2);
            L[iA + H]     = cadd(tC, p3);
            L[iA + H + Q] = csub(tC, p3);
        }
        __syncthreads();
        if (rho < 2) {
#pragma unroll
            for (int k = 0; k < 2; ++k) { pw1[k] = nw1[k]; pw2a[k] = nw2a[k]; pw2b[k] = nw2b[k]; }
        }
    }

    // ---- final radix-2 stage (t=22, stride 1) ----
    {
#pragma unroll
        for (int k = 0; k < 4; ++k) {
            const int pb = (bq << 2) + k;     // 0..63
            const int b  = pb << 1;
            const int iA = lam * 129 + b;
            const float2 A  = L[iA];
            const float2 Bv = L[iA + 1];
            const float2 p  = cmul(pr2[k], Bv);
            L[iA]     = cadd(A, p);
            L[iA + 1] = csub(A, p);
        }
    }
    __syncthreads();

    // ---- store fp32 with bit-reversal: out[rev7(g)*2^16 + h0*16 + lam] = L[lam][g] ----
    {
        const int l2 = (tid & 7) << 1;        // even lam (0..14)
        const int gb = tid >> 3;              // 0..31
#pragma unroll
        for (int k = 0; k < 4; ++k) {
            const int g    = gb + (k << 5);   // 0..127
            const int grev = (int)(__brev((unsigned)g) >> 25);   // rev7(g)
            const float2 a0 = L[l2 * 129 + g];
            const float2 a1 = L[(l2 + 1) * 129 + g];
            const size_t o = ((size_t)grev << 16) + (h0 << 4) + l2;
            *reinterpret_cast<float4*>(out + o) = make_float4(a0.x, a0.y, a1.x, a1.y);
        }
    }
}

extern "C" void kernel_launch(void* const* d_in, const int* in_sizes, int n_in,
                              void* d_out, int out_size, void* d_ws, size_t ws_size,
                              hipStream_t stream)
{
    (void)in_sizes; (void)n_in; (void)out_size; (void)ws_size;
    const float*  in = (const float*)d_in[0];
    const float2* wt = (const float2*)d_in[1];
    float2* outc = (float2*)d_out;
    uint4*  buf1 = (uint4*)d_ws;                          // 32 MB packed fp16
    uint4*  buf2 = (uint4*)((char*)d_ws + (32u << 20));   // 32 MB packed fp16

    fft_pass_a<<<2048, 256, 0, stream>>>(in,   wt, buf1);  // stages 0..7  : in   -> buf1 (fp16)
    fft_pass_b<<<2048, 256, 0, stream>>>(buf1, wt, buf2);  // stages 8..15 : buf1 -> buf2 (fp16)
    fft_pass_c<<<4096, 256, 0, stream>>>(buf2, wt, outc);  // stages 16..22: buf2 -> out (fp32, bitrev)
}